// Round 12
// baseline (222.694 us; speedup 1.0000x reference)
//
#include <hip/hip_runtime.h>
#include <cstdint>

// ---------------------------------------------------------------------------
// Causal self-attention block: fused prep (grid-stride) -> qkv GEMM (128x64
// tile, BK=64, drain-style, XCD-local A-stripe) -> flash attention
// (contiguous 128-query band blocks, 32x32 MFMA, async 3-buffer staging,
// MFMA-computed softmax row-sums) -> proj GEMM (64x64 tile, XCD-local).
// bf16 MFMA, fp32 accumulate. B=4 S=2048 E=768 H=12 D=64.
// NOTE: grid-wide-sync megakernel attempts (r7 cooperative launch, r8
// software barrier) both failed under this harness (capture-incompatible /
// GPU hang). 4-launch structure is the floor; boundaries ~60us structural.
// ---------------------------------------------------------------------------

typedef __bf16 bf16x8 __attribute__((ext_vector_type(8)));
typedef __bf16 bf16x4 __attribute__((ext_vector_type(4)));
typedef float  f32x4  __attribute__((ext_vector_type(4)));
typedef float  f32x16 __attribute__((ext_vector_type(16)));

#define MFMA16(a, b, c) __builtin_amdgcn_mfma_f32_16x16x32_bf16(a, b, c, 0, 0, 0)
#define MFMA32(a, b, c) __builtin_amdgcn_mfma_f32_32x32x16_bf16(a, b, c, 0, 0, 0)

static constexpr int Bb = 4, Ss = 2048, Ee = 768, Hh = 12, Dd = 64;
// softmax scale 1/8 folded with log2(e) so we can use raw v_exp_f32 (2^x)
#define QSCALE 0.18033688011112042f

__device__ __forceinline__ void gl2lds16(const void* g, void* l) {
  __builtin_amdgcn_global_load_lds(
      (const __attribute__((address_space(1))) void*)g,
      (__attribute__((address_space(3))) void*)l, 16, 0, 0);
}

__device__ __forceinline__ float fexp2(float x) {
#if __has_builtin(__builtin_amdgcn_exp2f)
  return __builtin_amdgcn_exp2f(x);
#else
  return exp2f(x);
#endif
}

// swap bits 2<->3: the shared MFMA k-slot permutation baked into K/V layouts
__device__ __forceinline__ int swap23(int x) {
  return (x & ~12) | ((x & 4) << 1) | ((x & 8) >> 1);
}

// ---------------------------------------------------------------------------
// fused prep, grid-stride over 6720 units (960 blocks x 7 units):
// units [0,6144) cast x f32->bf16 (1024 elems); [6144,6576) W_attn 64x64
// transpose-cast tile; [6576,6720) W_proj tile.
// ---------------------------------------------------------------------------
__global__ __launch_bounds__(256) void prep_all(
    const float* __restrict__ x, __bf16* __restrict__ xb,
    const float* __restrict__ Wa, __bf16* __restrict__ Wat,
    const float* __restrict__ Wp, __bf16* __restrict__ Wpt) {
  __shared__ float t[64][65];
  const int tid = threadIdx.x;
  for (int u = blockIdx.x; u < 6720; u += 960) {
    if (u < 6144) {  // 6144*1024 == 4*2048*768 exactly
      const int i = (u * 256 + tid) * 4;
      float4 v = *(const float4*)(x + i);
      bf16x4 o = {(__bf16)v.x, (__bf16)v.y, (__bf16)v.z, (__bf16)v.w};
      *(bf16x4*)(xb + i) = o;
      continue;
    }
    const float* W;
    __bf16* Wt;
    int K, N, bx, by;
    if (u < 6576) {
      W = Wa; Wt = Wat; K = 768; N = 2304;
      bx = (u - 6144) % 36; by = (u - 6144) / 36;
    } else {
      W = Wp; Wt = Wpt; K = 768; N = 768;
      bx = (u - 6576) % 12; by = (u - 6576) / 12;
    }
    const int k0 = by * 64, n0 = bx * 64;
    __syncthreads();  // protect t from previous unit's readers
#pragma unroll
    for (int i = 0; i < 16; ++i) {
      int lin = i * 256 + tid;
      int r = lin >> 6, c = lin & 63;
      t[r][c] = W[(size_t)(k0 + r) * N + n0 + c];
    }
    __syncthreads();
#pragma unroll
    for (int i = 0; i < 16; ++i) {
      int lin = i * 256 + tid;
      int r = lin >> 6, c = lin & 63;
      Wt[(size_t)(n0 + r) * K + k0 + c] = (__bf16)t[c][r];
    }
  }
}

// ---------------------------------------------------------------------------
// GEMM: C[M,N] = A[M,K] @ Bt[N,K]^T, TMxTN tile, BK=64, drain-style
// (r3/r6-proven schedule: two __syncthreads per k-step; resident-block TLP
// covers the drain). LDS rows are 128B -> XOR-(row&7) 16B-chunk swizzle on
// BOTH the staging source address and the fragment read.
//   MODE 0 (qkv):  128x64, LDS 24KB, grid 2304 = 9/CU (6 resident)
//   MODE 1 (proj): 64x64,  LDS 16KB, grid 1536 = 6/CU
// XCD-local mapping (1-D grid, blockIdx%8 -> XCD): each XCD owns MPX
// contiguous M-panels, M-inner/N-outer order -> co-dispatched blocks share
// one B-panel and the XCD's A-stripe stays L2-resident (r10-proven).
// MODE 0 epilogue: bias; Q^T [bh][d][s] plain prescaled 8B stores; K d-index
//                  and V^T s-index permuted via swap23.
// MODE 1 epilogue: bias, fp32 out.
// ---------------------------------------------------------------------------
template <int MODE, int TM, int TN>
__global__ __launch_bounds__(256, 6) void gemm_bt(
    const __bf16* __restrict__ A, const __bf16* __restrict__ Bt,
    const float* __restrict__ bias, __bf16* __restrict__ Qb,
    __bf16* __restrict__ Kb, __bf16* __restrict__ VTb,
    float* __restrict__ out, int K, int N) {
  __shared__ __align__(16) __bf16 As[TM * 64];
  __shared__ __align__(16) __bf16 Bs[TN * 64];
  const int tid = threadIdx.x;
  const int wave = tid >> 6, lane = tid & 63;
  const int quad = lane >> 4, c16 = lane & 15;

  // XCD-local mapping (bijective): lb&7 -> XCD, j -> (n outer, m inner)
  constexpr int MPX = (MODE == 0) ? 8 : 16;  // M-panels per XCD
  const int lb = blockIdx.x;
  const int xcd = lb & 7, j = lb >> 3;
  const int m0 = (xcd * MPX + (j % MPX)) * TM;
  const int n0 = (j / MPX) * TN;

  const int wm = (wave >> 1) * (TM / 2), wn = (wave & 1) * (TN / 2);
  constexpr int MI = TM / 32;  // 16-row fragment repeats per wave (M dim)
  constexpr int NI = TN / 32;  // 16-col fragment repeats per wave (N dim)
  constexpr int AWC = TM / 8;  // A wave-chunks (64 x 16B chunks each)
  constexpr int TWC = (TM + TN) / 8;  // total wave-chunks per k-step

  f32x4 acc[MI][NI] = {};

  for (int k0 = 0; k0 < K; k0 += 64) {
    __syncthreads();
#pragma unroll
    for (int i = 0; i < TWC / 4; ++i) {
      const int wc = i * 4 + wave;  // wave-chunk id, uniform within wave
      if (wc < AWC) {
        const int c = wc * 64 + lane;              // A chunk 0..TM*8-1
        const int row = c >> 3;                    // 0..TM-1
        const int kk = ((c & 7) ^ (row & 7)) * 8;  // swizzled source column
        gl2lds16(&A[(size_t)(m0 + row) * K + k0 + kk], &As[wc * 512]);
      } else {
        const int c = (wc - AWC) * 64 + lane;  // B chunk 0..TN*8-1
        const int row = c >> 3;                // 0..TN-1
        const int kk = ((c & 7) ^ (row & 7)) * 8;
        gl2lds16(&Bt[(size_t)(n0 + row) * K + k0 + kk],
                 &Bs[(wc - AWC) * 512]);
      }
    }
    __syncthreads();
#pragma unroll
    for (int h = 0; h < 2; ++h) {
      bf16x8 af[MI], bf[NI];
#pragma unroll
      for (int mi = 0; mi < MI; ++mi) {
        const int R = wm + mi * 16 + c16;
        af[mi] = *(const bf16x8*)&As[R * 64 + (((h * 4 + quad) ^ (R & 7)) * 8)];
      }
#pragma unroll
      for (int ni = 0; ni < NI; ++ni) {
        const int R = wn + ni * 16 + c16;
        bf[ni] = *(const bf16x8*)&Bs[R * 64 + (((h * 4 + quad) ^ (R & 7)) * 8)];
      }
#pragma unroll
      for (int mi = 0; mi < MI; ++mi)
#pragma unroll
        for (int ni = 0; ni < NI; ++ni)
          acc[mi][ni] = MFMA16(af[mi], bf[ni], acc[mi][ni]);
    }
  }

#pragma unroll
  for (int mi = 0; mi < MI; ++mi) {
#pragma unroll
    for (int ni = 0; ni < NI; ++ni) {
      const int gcol = n0 + wn + ni * 16 + c16;
      const float bv = bias[gcol];
      const int growb = m0 + wm + mi * 16 + quad * 4;
      if (MODE == 0) {
        const int which = gcol / Ee;
        const int e = gcol - which * Ee;
        const int hh = e >> 6, dd = e & 63;
        const int bb = growb >> 11, ss = growb & 2047;
        const size_t bh = (size_t)(bb * Hh + hh);
        if (which == 2) {  // V^T with permuted s: 4 consecutive ss stay packed
          const int ssp = swap23(ss);
          bf16x4 o;
#pragma unroll
          for (int r = 0; r < 4; ++r) o[r] = (__bf16)(acc[mi][ni][r] + bv);
          *(bf16x4*)&VTb[(bh * Dd + dd) * Ss + ssp] = o;
        } else if (which == 0) {  // Q^T [bh][d][s] plain, prescaled, 8B store
          bf16x4 o;
#pragma unroll
          for (int r = 0; r < 4; ++r)
            o[r] = (__bf16)((acc[mi][ni][r] + bv) * QSCALE);
          *(bf16x4*)&Qb[(bh * Dd + dd) * Ss + ss] = o;
        } else {  // K: permuted d
          const int ddp = swap23(dd);
#pragma unroll
          for (int r = 0; r < 4; ++r)
            Kb[(bh * Ss + ss + r) * Dd + ddp] = (__bf16)(acc[mi][ni][r] + bv);
        }
      } else {
#pragma unroll
        for (int r = 0; r < 4; ++r)
          out[(size_t)(growb + r) * N + gcol] = acc[mi][ni][r] + bv;
      }
    }
  }
}

// ---------------------------------------------------------------------------
// length-balanced (band, bh_local) assignment for flash blocks.
// Per XCD: 96 blocks = 6 bh x 16 bands; band i costs nkt = 2i+2 iterations.
// j-order interleaves classes L,S,M (period 3). Since 32 % 3 == 2, BOTH
// {3c,3c+1,3c+2} (fill-first) AND {c, c+32, c+64} (round-robin) CU triples
// get one block of each class -> per-CU iteration counts are balanced.
// ---------------------------------------------------------------------------
__device__ __forceinline__ void band_of(int j, int& band, int& bhl) {
  const int cls = j % 3, q = j / 3;
  if (cls == 0) {
    if (q < 30) { band = 15 - q / 6; bhl = q % 6; }
    else        { band = 10; bhl = q - 30; }
  } else if (cls == 1) {
    if (q < 30) { band = q / 6; bhl = q % 6; }
    else        { band = 5; bhl = q - 30; }
  } else {
    const int p = q >> 1, hi = !(q & 1);
    if (p < 4)       { band = hi ? 10 : 5; bhl = 2 + p; }
    else if (p < 10) { band = hi ? 9 : 6;  bhl = p - 4; }
    else             { band = hi ? 8 : 7;  bhl = p - 10; }
  }
}

// ---------------------------------------------------------------------------
// flash attention v9: r3-proven band structure + MFMA-computed softmax sums.
// Block = one contiguous 128-query band (wave w gets queries
// [128*band + 32w, +32)); async 3-buffer K/V staging via global_load_lds
// with XOR-(row&7) 16B-chunk swizzle; one raw s_barrier + counted vmcnt per
// iteration; prefetch a full iteration ahead. K/V layouts carry the swap23
// k-slot permutation; Q^T is plain [bh][d][s].
// NEW: row-sums Sum_k P[k][q] computed by 4 extra MFMA32(ones, pf[W]) on the
// idle matrix pipe instead of a 49-op VALU add-tree; l = lacc[0] (only reg 0
// is kept consistent under grow-rescale -- later MFMAs add uniformly, rows
// 1..15 are never read). lacc sums the same bf16 P that PV consumes.
// ---------------------------------------------------------------------------
__global__ __launch_bounds__(256, 3) void flash_attn(
    const __bf16* __restrict__ Qb, const __bf16* __restrict__ Kb,
    const __bf16* __restrict__ VTb, const int* __restrict__ amask,
    __bf16* __restrict__ Yb) {
  const int bid = blockIdx.x;
  const int xcd = bid & 7, j = bid >> 3;
  int band, bhl;
  band_of(j, band, bhl);
  const int bh = xcd * 6 + bhl;  // 6 (b,h) per XCD for L2 locality
  const int b = bh / Hh, h = bh - b * Hh;
  const int tid = threadIdx.x, w = tid >> 6, lane = tid & 63;
  const int hl = lane >> 5, l31 = lane & 31;
  const int r7 = l31 & 7;

  const int qs = band * 128 + w * 32;
  const int qg = qs + l31;                // this lane's query
  const int ktmax = 2 * band + (w >> 1);  // last key-tile for this wave
  const int nkt = 2 * band + 2;           // block-uniform iteration count

  const __bf16* Qp = Qb + (size_t)bh * Dd * Ss;  // Q^T [d][s]
  const __bf16* Kp = Kb + (size_t)bh * Ss * Dd;
  const __bf16* Vp = VTb + (size_t)bh * Dd * Ss;

  __shared__ __align__(16) __bf16 Ksh[3 * 64 * 64];  // 3 x 8KB
  __shared__ __align__(16) __bf16 Vsh[3 * 64 * 64];  // 3 x 8KB
  __shared__ uint64_t ballots[32];

  // Q fragments: one-time strided gather from plain Q^T; the swap23 k-slot
  // permutation folded into d: d = wd*16 + hl*4 + (jj&3) + 2*(jj&4)
  bf16x8 qf[4];
#pragma unroll
  for (int wd = 0; wd < 4; ++wd) {
    bf16x8 f;
#pragma unroll
    for (int jj = 0; jj < 8; ++jj)
      f[jj] = Qp[(size_t)(wd * 16 + hl * 4 + (jj & 3) + ((jj & 4) << 1)) * Ss +
                 qg];
    qf[wd] = f;
  }

  // all-ones A-operand for the sum MFMAs
  const __bf16 kone = (__bf16)1.0f;
  const bf16x8 vones = {kone, kone, kone, kone, kone, kone, kone, kone};

  // precompute attention-mask ballots for all 32 key-tiles (8 per wave)
#pragma unroll
  for (int i = 0; i < 8; ++i) {
    const int t = w * 8 + i;
    const uint64_t ball = __ballot(amask[b * Ss + t * 64 + lane] != 0);
    if (lane == 0) ballots[t] = ball;
  }
  asm volatile("s_waitcnt lgkmcnt(0)" ::: "memory");  // publish own writes

  // async stage of tile kt into buffer buf (4 gl2lds16 per thread)
  auto stage = [&](int kt, int buf) {
    __bf16* kb = &Ksh[buf * 4096];
    __bf16* vb = &Vsh[buf * 4096];
    const char* ksrc = (const char*)(Kp + (size_t)kt * 64 * Dd);
    const char* vsrc = (const char*)Vp + (size_t)kt * 128;
#pragma unroll
    for (int i = 0; i < 2; ++i) {
      const int cb = i * 256 + w * 64;     // wave-uniform chunk base
      const int p = cb + lane;             // this lane's chunk 0..511
      const int row = p >> 3;
      const int cc = (p & 7) ^ (row & 7);  // XOR swizzle
      gl2lds16(ksrc + (size_t)row * 128 + cc * 16, &kb[cb * 8]);
      gl2lds16(vsrc + (size_t)row * 4096 + cc * 16, &vb[cb * 8]);
    }
  };

  stage(0, 0);
  stage(1, 1);  // nkt >= 2 always

  f32x16 yacc[2] = {};  // Y^T[d = 32dt + (r&3)+8(r>>2)+4hl][q = l31]
  f32x16 lacc = {};     // row sums: every reg = Sum_k P[k][q]; reg 0 is live
  float m_i = -30000.f;

  for (int kt = 0; kt < nkt; ++kt) {
    // wait for tile kt's staging (keep kt+1's 4 loads in flight), then
    // barrier: publishes buf[kt] and proves everyone left buf[(kt+2)%3]
    if (kt + 1 < nkt)
      asm volatile("s_waitcnt vmcnt(4)\n\ts_barrier" ::: "memory");
    else
      asm volatile("s_waitcnt vmcnt(0)\n\ts_barrier" ::: "memory");
    if (kt + 2 < nkt) stage(kt + 2, (kt + 2) % 3);

    if (kt > ktmax) continue;  // waves 0,1 idle only on the last tile
    const int k0 = kt * 64;
    const __bf16* kb = &Ksh[(kt % 3) * 4096];
    const __bf16* vb = &Vsh[(kt % 3) * 4096];

    // S^T = K @ Q^T over two 32-key groups (C rows = keys, cols = queries)
    f32x16 sg[2];
    __builtin_amdgcn_s_setprio(1);
#pragma unroll
    for (int g = 0; g < 2; ++g) {
      f32x16 acc = {};
#pragma unroll
      for (int wd = 0; wd < 4; ++wd) {
        const bf16x8 kf = *(const bf16x8*)&kb[(g * 32 + l31) * 64 +
                                             (((2 * wd + hl) ^ r7) * 8)];
        acc = MFMA32(kf, qf[wd], acc);
      }
      sg[g] = acc;
    }
    __builtin_amdgcn_s_setprio(0);

    // causal mask: only tiles overlapping this wave's diagonal
    if (k0 + 63 > qs) {
#pragma unroll
      for (int g = 0; g < 2; ++g)
#pragma unroll
        for (int r = 0; r < 16; ++r) {
          const int key = k0 + g * 32 + (r & 3) + 8 * (r >> 2) + 4 * hl;
          sg[g][r] = (key <= qg) ? sg[g][r] : -30000.f;
        }
    }
    // attention mask: wave-uniform skip when tile fully valid
    const uint64_t mball = ballots[kt];
    if (mball != ~0ull) {
#pragma unroll
      for (int g = 0; g < 2; ++g)
#pragma unroll
        for (int r = 0; r < 16; ++r) {
          const int kr = g * 32 + (r & 3) + 8 * (r >> 2) + 4 * hl;
          sg[g][r] = ((mball >> kr) & 1) ? sg[g][r] : -30000.f;
        }
    }

    // running max: max3-friendly tree (depth ~5) + one cross-half shuffle
    float tm[8];
#pragma unroll
    for (int r = 0; r < 8; ++r)
      tm[r] = fmaxf(fmaxf(sg[0][r], sg[0][r + 8]),
                    fmaxf(sg[1][r], sg[1][r + 8]));
    float mA = fmaxf(fmaxf(fmaxf(tm[0], tm[1]), fmaxf(tm[2], tm[3])),
                     fmaxf(fmaxf(tm[4], tm[5]), fmaxf(tm[6], tm[7])));
    const float mx = fmaxf(mA, __shfl_xor(mA, 32));

    // defer-max (T13): skip O/l rescale when max grows <= 2^11.5
    const bool grow = !__all(mx <= m_i + 11.5f);
    const float mnew = grow ? fmaxf(m_i, mx) : m_i;

    // P = 2^(S - m); no VALU sum tree -- sums come from the ones-MFMA below
#pragma unroll
    for (int g = 0; g < 2; ++g)
#pragma unroll
      for (int r = 0; r < 16; ++r) sg[g][r] = fexp2(sg[g][r] - mnew);

    if (grow) {
      const float alpha = fexp2(m_i - mnew);
      m_i = mnew;
      lacc[0] *= alpha;  // only reg 0 is read; later MFMAs add uniformly
#pragma unroll
      for (int dt = 0; dt < 2; ++dt)
#pragma unroll
        for (int r = 0; r < 16; ++r) yacc[dt][r] *= alpha;
    }

    // P^T B-fragments = S^T C-register groups (shared k-slot permutation)
    bf16x8 pf[4];
#pragma unroll
    for (int W = 0; W < 4; ++W) {
      bf16x8 f;
#pragma unroll
      for (int jj = 0; jj < 8; ++jj)
        f[jj] = (__bf16)sg[W >> 1][8 * (W & 1) + jj];
      pf[W] = f;
    }

    // Y^T += V^T @ P^T ; lacc += ones @ P^T (row sums on the matrix pipe)
    __builtin_amdgcn_s_setprio(1);
#pragma unroll
    for (int W = 0; W < 4; ++W) {
      const bf16x8 vf0 = *(const bf16x8*)&vb[(l31)*64 + (((2 * W + hl) ^ r7) * 8)];
      const bf16x8 vf1 =
          *(const bf16x8*)&vb[(32 + l31) * 64 + (((2 * W + hl) ^ r7) * 8)];
      yacc[0] = MFMA32(vf0, pf[W], yacc[0]);
      yacc[1] = MFMA32(vf1, pf[W], yacc[1]);
      lacc = MFMA32(vones, pf[W], lacc);
    }
    __builtin_amdgcn_s_setprio(0);
  }

  // normalize; write Y [B,S,E] bf16 (unpermuted -- feeds gemm2)
  const float inv = 1.f / lacc[0];
  __bf16* yrow = Yb + (size_t)(b * Ss + qg) * Ee + h * Dd;
#pragma unroll
  for (int dt = 0; dt < 2; ++dt)
#pragma unroll
    for (int sreg = 0; sreg < 4; ++sreg) {
      bf16x4 o;
#pragma unroll
      for (int r = 0; r < 4; ++r)
        o[r] = (__bf16)(yacc[dt][sreg * 4 + r] * inv);
      *(bf16x4*)&yrow[dt * 32 + sreg * 8 + hl * 4] = o;
    }
}

// ---------------------------------------------------------------------------
// launch
// ---------------------------------------------------------------------------
extern "C" void kernel_launch(void* const* d_in, const int* in_sizes, int n_in,
                              void* d_out, int out_size, void* d_ws,
                              size_t ws_size, hipStream_t stream) {
  const float* x      = (const float*)d_in[0];
  const float* W_attn = (const float*)d_in[1];
  const float* b_attn = (const float*)d_in[2];
  const float* W_proj = (const float*)d_in[3];
  const float* b_proj = (const float*)d_in[4];
  const int* att_mask = (const int*)d_in[5];
  float* out = (float*)d_out;

  char* ws = (char*)d_ws;
  __bf16* xb  = (__bf16*)(ws);              // 12,582,912  x as bf16 / later Y
  __bf16* Wat = (__bf16*)(ws + 12582912);   //  3,538,944  W_attn^T bf16
  __bf16* Wpt = (__bf16*)(ws + 16121856);   //  1,179,648  W_proj^T bf16
  __bf16* Qb  = (__bf16*)(ws + 17301504);   // Q^T [B,H,D,S] plain, x log2e/8
  __bf16* Kb  = (__bf16*)(ws + 29884416);   // K [B,H,S,D] perm
  __bf16* VTb = (__bf16*)(ws + 42467328);   // V^T [B,H,D,S] perm
  __bf16* Yb  = xb;

  prep_all<<<960, 256, 0, stream>>>(x, xb, W_attn, Wat, W_proj, Wpt);

  // qkv: 2304 blocks = 8 XCD x (36 N-panels x 8 M-panels, M inner), 128x64
  gemm_bt<0, 128, 64><<<2304, 256, 0, stream>>>(
      xb, Wat, b_attn, Qb, Kb, VTb, nullptr, Ee, 3 * Ee);
  flash_attn<<<768, 256, 0, stream>>>(Qb, Kb, VTb, att_mask, Yb);
  // proj: 1536 blocks = 8 XCD x (12 N-panels x 16 M-panels, M inner), 64x64
  gemm_bt<1, 64, 64><<<1536, 256, 0, stream>>>(
      Yb, Wpt, b_proj, nullptr, nullptr, nullptr, out, Ee, Ee);
}

// Round 13
// 200.007 us; speedup vs baseline: 1.1134x; 1.1134x over previous
//
#include <hip/hip_runtime.h>
#include <cstdint>

// ---------------------------------------------------------------------------
// Causal self-attention block: fused prep (grid-stride) -> qkv GEMM (128x64
// tile, BK=64, drain-style, 6 blocks/CU, XCD-local A-stripe) -> flash
// attention (contiguous 128-query band blocks, 32x32 MFMA, async 3-buffer
// staging) -> proj GEMM (64x64 tile, 6 blocks/CU, XCD-local).
// bf16 MFMA, fp32 accumulate. B=4 S=2048 E=768 H=12 D=64.
// SESSION-FINAL (r13 = r11 verbatim, the measured optimum: 201.1us).
// Closed lines, each measured: megakernel/grid-sync (r7 capture-fail, r8
// hang); flash K/V direct-from-L2 (r1/r4: latency-bound regression); flash
// MFMA-computed softmax sums (r12: +10us, MFMA latency on critical path);
// GEMM source-pipelining (r5: neutral, occupancy loss); boundaries ~60us
// structural in this 4-launch harness.
// ---------------------------------------------------------------------------

typedef __bf16 bf16x8 __attribute__((ext_vector_type(8)));
typedef __bf16 bf16x4 __attribute__((ext_vector_type(4)));
typedef float  f32x4  __attribute__((ext_vector_type(4)));
typedef float  f32x16 __attribute__((ext_vector_type(16)));

#define MFMA16(a, b, c) __builtin_amdgcn_mfma_f32_16x16x32_bf16(a, b, c, 0, 0, 0)
#define MFMA32(a, b, c) __builtin_amdgcn_mfma_f32_32x32x16_bf16(a, b, c, 0, 0, 0)

static constexpr int Bb = 4, Ss = 2048, Ee = 768, Hh = 12, Dd = 64;
// softmax scale 1/8 folded with log2(e) so we can use raw v_exp_f32 (2^x)
#define QSCALE 0.18033688011112042f

__device__ __forceinline__ void gl2lds16(const void* g, void* l) {
  __builtin_amdgcn_global_load_lds(
      (const __attribute__((address_space(1))) void*)g,
      (__attribute__((address_space(3))) void*)l, 16, 0, 0);
}

__device__ __forceinline__ float fexp2(float x) {
#if __has_builtin(__builtin_amdgcn_exp2f)
  return __builtin_amdgcn_exp2f(x);
#else
  return exp2f(x);
#endif
}

// swap bits 2<->3: the shared MFMA k-slot permutation baked into K/V layouts
__device__ __forceinline__ int swap23(int x) {
  return (x & ~12) | ((x & 4) << 1) | ((x & 8) >> 1);
}

// ---------------------------------------------------------------------------
// fused prep, grid-stride over 6720 units (960 blocks x 7 units):
// units [0,6144) cast x f32->bf16 (1024 elems); [6144,6576) W_attn 64x64
// transpose-cast tile; [6576,6720) W_proj tile.
// ---------------------------------------------------------------------------
__global__ __launch_bounds__(256) void prep_all(
    const float* __restrict__ x, __bf16* __restrict__ xb,
    const float* __restrict__ Wa, __bf16* __restrict__ Wat,
    const float* __restrict__ Wp, __bf16* __restrict__ Wpt) {
  __shared__ float t[64][65];
  const int tid = threadIdx.x;
  for (int u = blockIdx.x; u < 6720; u += 960) {
    if (u < 6144) {  // 6144*1024 == 4*2048*768 exactly
      const int i = (u * 256 + tid) * 4;
      float4 v = *(const float4*)(x + i);
      bf16x4 o = {(__bf16)v.x, (__bf16)v.y, (__bf16)v.z, (__bf16)v.w};
      *(bf16x4*)(xb + i) = o;
      continue;
    }
    const float* W;
    __bf16* Wt;
    int K, N, bx, by;
    if (u < 6576) {
      W = Wa; Wt = Wat; K = 768; N = 2304;
      bx = (u - 6144) % 36; by = (u - 6144) / 36;
    } else {
      W = Wp; Wt = Wpt; K = 768; N = 768;
      bx = (u - 6576) % 12; by = (u - 6576) / 12;
    }
    const int k0 = by * 64, n0 = bx * 64;
    __syncthreads();  // protect t from previous unit's readers
#pragma unroll
    for (int i = 0; i < 16; ++i) {
      int lin = i * 256 + tid;
      int r = lin >> 6, c = lin & 63;
      t[r][c] = W[(size_t)(k0 + r) * N + n0 + c];
    }
    __syncthreads();
#pragma unroll
    for (int i = 0; i < 16; ++i) {
      int lin = i * 256 + tid;
      int r = lin >> 6, c = lin & 63;
      Wt[(size_t)(n0 + r) * K + k0 + c] = (__bf16)t[c][r];
    }
  }
}

// ---------------------------------------------------------------------------
// GEMM: C[M,N] = A[M,K] @ Bt[N,K]^T, TMxTN tile, BK=64, drain-style
// (r3/r6-proven schedule: two __syncthreads per k-step; resident-block TLP
// covers the drain). LDS rows are 128B -> XOR-(row&7) 16B-chunk swizzle on
// BOTH the staging source address and the fragment read.
//   MODE 0 (qkv):  128x64, LDS 24KB, grid 2304 = 9/CU (6 resident)
//   MODE 1 (proj): 64x64,  LDS 16KB, grid 1536 = 6/CU
// XCD-local mapping (1-D grid, blockIdx%8 -> XCD): each XCD owns MPX
// contiguous M-panels, M-inner/N-outer order -> co-dispatched blocks share
// one B-panel and the XCD's A-stripe stays L2-resident (r10-proven).
// MODE 0 epilogue: bias; Q^T [bh][d][s] plain prescaled 8B stores; K d-index
//                  and V^T s-index permuted via swap23.
// MODE 1 epilogue: bias, fp32 out.
// ---------------------------------------------------------------------------
template <int MODE, int TM, int TN>
__global__ __launch_bounds__(256, 6) void gemm_bt(
    const __bf16* __restrict__ A, const __bf16* __restrict__ Bt,
    const float* __restrict__ bias, __bf16* __restrict__ Qb,
    __bf16* __restrict__ Kb, __bf16* __restrict__ VTb,
    float* __restrict__ out, int K, int N) {
  __shared__ __align__(16) __bf16 As[TM * 64];
  __shared__ __align__(16) __bf16 Bs[TN * 64];
  const int tid = threadIdx.x;
  const int wave = tid >> 6, lane = tid & 63;
  const int quad = lane >> 4, c16 = lane & 15;

  // XCD-local mapping (bijective): lb&7 -> XCD, j -> (n outer, m inner)
  constexpr int MPX = (MODE == 0) ? 8 : 16;  // M-panels per XCD
  const int lb = blockIdx.x;
  const int xcd = lb & 7, j = lb >> 3;
  const int m0 = (xcd * MPX + (j % MPX)) * TM;
  const int n0 = (j / MPX) * TN;

  const int wm = (wave >> 1) * (TM / 2), wn = (wave & 1) * (TN / 2);
  constexpr int MI = TM / 32;  // 16-row fragment repeats per wave (M dim)
  constexpr int NI = TN / 32;  // 16-col fragment repeats per wave (N dim)
  constexpr int AWC = TM / 8;  // A wave-chunks (64 x 16B chunks each)
  constexpr int TWC = (TM + TN) / 8;  // total wave-chunks per k-step

  f32x4 acc[MI][NI] = {};

  for (int k0 = 0; k0 < K; k0 += 64) {
    __syncthreads();
#pragma unroll
    for (int i = 0; i < TWC / 4; ++i) {
      const int wc = i * 4 + wave;  // wave-chunk id, uniform within wave
      if (wc < AWC) {
        const int c = wc * 64 + lane;              // A chunk 0..TM*8-1
        const int row = c >> 3;                    // 0..TM-1
        const int kk = ((c & 7) ^ (row & 7)) * 8;  // swizzled source column
        gl2lds16(&A[(size_t)(m0 + row) * K + k0 + kk], &As[wc * 512]);
      } else {
        const int c = (wc - AWC) * 64 + lane;  // B chunk 0..TN*8-1
        const int row = c >> 3;                // 0..TN-1
        const int kk = ((c & 7) ^ (row & 7)) * 8;
        gl2lds16(&Bt[(size_t)(n0 + row) * K + k0 + kk],
                 &Bs[(wc - AWC) * 512]);
      }
    }
    __syncthreads();
#pragma unroll
    for (int h = 0; h < 2; ++h) {
      bf16x8 af[MI], bf[NI];
#pragma unroll
      for (int mi = 0; mi < MI; ++mi) {
        const int R = wm + mi * 16 + c16;
        af[mi] = *(const bf16x8*)&As[R * 64 + (((h * 4 + quad) ^ (R & 7)) * 8)];
      }
#pragma unroll
      for (int ni = 0; ni < NI; ++ni) {
        const int R = wn + ni * 16 + c16;
        bf[ni] = *(const bf16x8*)&Bs[R * 64 + (((h * 4 + quad) ^ (R & 7)) * 8)];
      }
#pragma unroll
      for (int mi = 0; mi < MI; ++mi)
#pragma unroll
        for (int ni = 0; ni < NI; ++ni)
          acc[mi][ni] = MFMA16(af[mi], bf[ni], acc[mi][ni]);
    }
  }

#pragma unroll
  for (int mi = 0; mi < MI; ++mi) {
#pragma unroll
    for (int ni = 0; ni < NI; ++ni) {
      const int gcol = n0 + wn + ni * 16 + c16;
      const float bv = bias[gcol];
      const int growb = m0 + wm + mi * 16 + quad * 4;
      if (MODE == 0) {
        const int which = gcol / Ee;
        const int e = gcol - which * Ee;
        const int hh = e >> 6, dd = e & 63;
        const int bb = growb >> 11, ss = growb & 2047;
        const size_t bh = (size_t)(bb * Hh + hh);
        if (which == 2) {  // V^T with permuted s: 4 consecutive ss stay packed
          const int ssp = swap23(ss);
          bf16x4 o;
#pragma unroll
          for (int r = 0; r < 4; ++r) o[r] = (__bf16)(acc[mi][ni][r] + bv);
          *(bf16x4*)&VTb[(bh * Dd + dd) * Ss + ssp] = o;
        } else if (which == 0) {  // Q^T [bh][d][s] plain, prescaled, 8B store
          bf16x4 o;
#pragma unroll
          for (int r = 0; r < 4; ++r)
            o[r] = (__bf16)((acc[mi][ni][r] + bv) * QSCALE);
          *(bf16x4*)&Qb[(bh * Dd + dd) * Ss + ss] = o;
        } else {  // K: permuted d
          const int ddp = swap23(dd);
#pragma unroll
          for (int r = 0; r < 4; ++r)
            Kb[(bh * Ss + ss + r) * Dd + ddp] = (__bf16)(acc[mi][ni][r] + bv);
        }
      } else {
#pragma unroll
        for (int r = 0; r < 4; ++r)
          out[(size_t)(growb + r) * N + gcol] = acc[mi][ni][r] + bv;
      }
    }
  }
}

// ---------------------------------------------------------------------------
// length-balanced (band, bh_local) assignment for flash blocks.
// Per XCD: 96 blocks = 6 bh x 16 bands; band i costs nkt = 2i+2 iterations.
// j-order interleaves classes L,S,M (period 3). Since 32 % 3 == 2, BOTH
// {3c,3c+1,3c+2} (fill-first) AND {c, c+32, c+64} (round-robin) CU triples
// get one block of each class -> per-CU iteration counts are balanced.
// ---------------------------------------------------------------------------
__device__ __forceinline__ void band_of(int j, int& band, int& bhl) {
  const int cls = j % 3, q = j / 3;
  if (cls == 0) {
    if (q < 30) { band = 15 - q / 6; bhl = q % 6; }
    else        { band = 10; bhl = q - 30; }
  } else if (cls == 1) {
    if (q < 30) { band = q / 6; bhl = q % 6; }
    else        { band = 5; bhl = q - 30; }
  } else {
    const int p = q >> 1, hi = !(q & 1);
    if (p < 4)       { band = hi ? 10 : 5; bhl = 2 + p; }
    else if (p < 10) { band = hi ? 9 : 6;  bhl = p - 4; }
    else             { band = hi ? 8 : 7;  bhl = p - 10; }
  }
}

// ---------------------------------------------------------------------------
// flash attention v7 (round-3/6/11-proven, ~60us): block = one contiguous
// 128-query band (wave w gets queries [128*band + 32w, +32)); async 3-buffer
// K/V staging via global_load_lds with XOR-(row&7) 16B-chunk swizzle; one
// raw s_barrier + counted vmcnt per iteration; prefetch a full iteration
// ahead. K/V layouts carry the swap23 k-slot permutation; Q^T is plain
// [bh][d][s] (permutation folded into the one-time gather).
// ---------------------------------------------------------------------------
__global__ __launch_bounds__(256, 3) void flash_attn(
    const __bf16* __restrict__ Qb, const __bf16* __restrict__ Kb,
    const __bf16* __restrict__ VTb, const int* __restrict__ amask,
    __bf16* __restrict__ Yb) {
  const int bid = blockIdx.x;
  const int xcd = bid & 7, j = bid >> 3;
  int band, bhl;
  band_of(j, band, bhl);
  const int bh = xcd * 6 + bhl;  // 6 (b,h) per XCD for L2 locality
  const int b = bh / Hh, h = bh - b * Hh;
  const int tid = threadIdx.x, w = tid >> 6, lane = tid & 63;
  const int hl = lane >> 5, l31 = lane & 31;
  const int r7 = l31 & 7;

  const int qs = band * 128 + w * 32;
  const int qg = qs + l31;                // this lane's query
  const int ktmax = 2 * band + (w >> 1);  // last key-tile for this wave
  const int nkt = 2 * band + 2;           // block-uniform iteration count

  const __bf16* Qp = Qb + (size_t)bh * Dd * Ss;  // Q^T [d][s]
  const __bf16* Kp = Kb + (size_t)bh * Ss * Dd;
  const __bf16* Vp = VTb + (size_t)bh * Dd * Ss;

  __shared__ __align__(16) __bf16 Ksh[3 * 64 * 64];  // 3 x 8KB
  __shared__ __align__(16) __bf16 Vsh[3 * 64 * 64];  // 3 x 8KB
  __shared__ uint64_t ballots[32];

  // Q fragments: one-time strided gather from plain Q^T; the swap23 k-slot
  // permutation folded into d: d = wd*16 + hl*4 + (jj&3) + 2*(jj&4)
  bf16x8 qf[4];
#pragma unroll
  for (int wd = 0; wd < 4; ++wd) {
    bf16x8 f;
#pragma unroll
    for (int jj = 0; jj < 8; ++jj)
      f[jj] = Qp[(size_t)(wd * 16 + hl * 4 + (jj & 3) + ((jj & 4) << 1)) * Ss +
                 qg];
    qf[wd] = f;
  }

  // precompute attention-mask ballots for all 32 key-tiles (8 per wave)
#pragma unroll
  for (int i = 0; i < 8; ++i) {
    const int t = w * 8 + i;
    const uint64_t ball = __ballot(amask[b * Ss + t * 64 + lane] != 0);
    if (lane == 0) ballots[t] = ball;
  }
  asm volatile("s_waitcnt lgkmcnt(0)" ::: "memory");  // publish own writes

  // async stage of tile kt into buffer buf (4 gl2lds16 per thread)
  auto stage = [&](int kt, int buf) {
    __bf16* kb = &Ksh[buf * 4096];
    __bf16* vb = &Vsh[buf * 4096];
    const char* ksrc = (const char*)(Kp + (size_t)kt * 64 * Dd);
    const char* vsrc = (const char*)Vp + (size_t)kt * 128;
#pragma unroll
    for (int i = 0; i < 2; ++i) {
      const int cb = i * 256 + w * 64;     // wave-uniform chunk base
      const int p = cb + lane;             // this lane's chunk 0..511
      const int row = p >> 3;
      const int cc = (p & 7) ^ (row & 7);  // XOR swizzle
      gl2lds16(ksrc + (size_t)row * 128 + cc * 16, &kb[cb * 8]);
      gl2lds16(vsrc + (size_t)row * 4096 + cc * 16, &vb[cb * 8]);
    }
  };

  stage(0, 0);
  stage(1, 1);  // nkt >= 2 always

  f32x16 yacc[2] = {};  // Y^T[d = 32dt + (r&3)+8(r>>2)+4hl][q = l31]
  float m_i = -30000.f, l_i = 0.f;

  for (int kt = 0; kt < nkt; ++kt) {
    // wait for tile kt's staging (keep kt+1's 4 loads in flight), then
    // barrier: publishes buf[kt] and proves everyone left buf[(kt+2)%3]
    if (kt + 1 < nkt)
      asm volatile("s_waitcnt vmcnt(4)\n\ts_barrier" ::: "memory");
    else
      asm volatile("s_waitcnt vmcnt(0)\n\ts_barrier" ::: "memory");
    if (kt + 2 < nkt) stage(kt + 2, (kt + 2) % 3);

    if (kt > ktmax) continue;  // waves 0,1 idle only on the last tile
    const int k0 = kt * 64;
    const __bf16* kb = &Ksh[(kt % 3) * 4096];
    const __bf16* vb = &Vsh[(kt % 3) * 4096];

    // S^T = K @ Q^T over two 32-key groups (C rows = keys, cols = queries)
    f32x16 sg[2];
    __builtin_amdgcn_s_setprio(1);
#pragma unroll
    for (int g = 0; g < 2; ++g) {
      f32x16 acc = {};
#pragma unroll
      for (int wd = 0; wd < 4; ++wd) {
        const bf16x8 kf = *(const bf16x8*)&kb[(g * 32 + l31) * 64 +
                                             (((2 * wd + hl) ^ r7) * 8)];
        acc = MFMA32(kf, qf[wd], acc);
      }
      sg[g] = acc;
    }
    __builtin_amdgcn_s_setprio(0);

    // causal mask: only tiles overlapping this wave's diagonal
    if (k0 + 63 > qs) {
#pragma unroll
      for (int g = 0; g < 2; ++g)
#pragma unroll
        for (int r = 0; r < 16; ++r) {
          const int key = k0 + g * 32 + (r & 3) + 8 * (r >> 2) + 4 * hl;
          sg[g][r] = (key <= qg) ? sg[g][r] : -30000.f;
        }
    }
    // attention mask: wave-uniform skip when tile fully valid
    const uint64_t mball = ballots[kt];
    if (mball != ~0ull) {
#pragma unroll
      for (int g = 0; g < 2; ++g)
#pragma unroll
        for (int r = 0; r < 16; ++r) {
          const int kr = g * 32 + (r & 3) + 8 * (r >> 2) + 4 * hl;
          sg[g][r] = ((mball >> kr) & 1) ? sg[g][r] : -30000.f;
        }
    }

    // online softmax in log2 domain; row = lane's q; tree-shaped reductions
    float tm[16];
#pragma unroll
    for (int r = 0; r < 16; ++r) tm[r] = fmaxf(sg[0][r], sg[1][r]);
#pragma unroll
    for (int off = 8; off >= 1; off >>= 1)
#pragma unroll
      for (int r = 0; r < 8; ++r)
        if (r < off) tm[r] = fmaxf(tm[r], tm[r + off]);
    const float mx = fmaxf(tm[0], __shfl_xor(tm[0], 32));

    // defer-max (T13): skip O/l rescale when max grows <= 2^11.5
    const bool grow = !__all(mx <= m_i + 11.5f);
    const float mnew = grow ? fmaxf(m_i, mx) : m_i;

    float ts[16];
#pragma unroll
    for (int r = 0; r < 16; ++r) {
      const float e0 = fexp2(sg[0][r] - mnew);
      const float e1 = fexp2(sg[1][r] - mnew);
      sg[0][r] = e0;
      sg[1][r] = e1;
      ts[r] = e0 + e1;
    }
#pragma unroll
    for (int off = 8; off >= 1; off >>= 1)
#pragma unroll
      for (int r = 0; r < 8; ++r)
        if (r < off) ts[r] += ts[r + off];
    const float rs = ts[0] + __shfl_xor(ts[0], 32);

    if (grow) {
      const float alpha = fexp2(m_i - mnew);
      l_i *= alpha;
      m_i = mnew;
#pragma unroll
      for (int dt = 0; dt < 2; ++dt)
#pragma unroll
        for (int r = 0; r < 16; ++r) yacc[dt][r] *= alpha;
    }
    l_i += rs;

    // P^T B-fragments = S^T C-register groups (shared k-slot permutation)
    bf16x8 pf[4];
#pragma unroll
    for (int W = 0; W < 4; ++W) {
      bf16x8 f;
#pragma unroll
      for (int jj = 0; jj < 8; ++jj)
        f[jj] = (__bf16)sg[W >> 1][8 * (W & 1) + jj];
      pf[W] = f;
    }

    // Y^T += V^T @ P^T
    __builtin_amdgcn_s_setprio(1);
#pragma unroll
    for (int dt = 0; dt < 2; ++dt)
#pragma unroll
      for (int W = 0; W < 4; ++W) {
        const bf16x8 vf = *(const bf16x8*)&vb[(dt * 32 + l31) * 64 +
                                             (((2 * W + hl) ^ r7) * 8)];
        yacc[dt] = MFMA32(vf, pf[W], yacc[dt]);
      }
    __builtin_amdgcn_s_setprio(0);
  }

  // normalize; write Y [B,S,E] bf16 (unpermuted -- feeds gemm2)
  const float inv = 1.f / l_i;
  __bf16* yrow = Yb + (size_t)(b * Ss + qg) * Ee + h * Dd;
#pragma unroll
  for (int dt = 0; dt < 2; ++dt)
#pragma unroll
    for (int sreg = 0; sreg < 4; ++sreg) {
      bf16x4 o;
#pragma unroll
      for (int r = 0; r < 4; ++r)
        o[r] = (__bf16)(yacc[dt][sreg * 4 + r] * inv);
      *(bf16x4*)&yrow[dt * 32 + sreg * 8 + hl * 4] = o;
    }
}

// ---------------------------------------------------------------------------
// launch
// ---------------------------------------------------------------------------
extern "C" void kernel_launch(void* const* d_in, const int* in_sizes, int n_in,
                              void* d_out, int out_size, void* d_ws,
                              size_t ws_size, hipStream_t stream) {
  const float* x      = (const float*)d_in[0];
  const float* W_attn = (const float*)d_in[1];
  const float* b_attn = (const float*)d_in[2];
  const float* W_proj = (const float*)d_in[3];
  const float* b_proj = (const float*)d_in[4];
  const int* att_mask = (const int*)d_in[5];
  float* out = (float*)d_out;

  char* ws = (char*)d_ws;
  __bf16* xb  = (__bf16*)(ws);              // 12,582,912  x as bf16 / later Y
  __bf16* Wat = (__bf16*)(ws + 12582912);   //  3,538,944  W_attn^T bf16
  __bf16* Wpt = (__bf16*)(ws + 16121856);   //  1,179,648  W_proj^T bf16
  __bf16* Qb  = (__bf16*)(ws + 17301504);   // Q^T [B,H,D,S] plain, x log2e/8
  __bf16* Kb  = (__bf16*)(ws + 29884416);   // K [B,H,S,D] perm
  __bf16* VTb = (__bf16*)(ws + 42467328);   // V^T [B,H,D,S] perm
  __bf16* Yb  = xb;

  prep_all<<<960, 256, 0, stream>>>(x, xb, W_attn, Wat, W_proj, Wpt);

  // qkv: 2304 blocks = 8 XCD x (36 N-panels x 8 M-panels, M inner), 128x64
  gemm_bt<0, 128, 64><<<2304, 256, 0, stream>>>(
      xb, Wat, b_attn, Qb, Kb, VTb, nullptr, Ee, 3 * Ee);
  flash_attn<<<768, 256, 0, stream>>>(Qb, Kb, VTb, att_mask, Yb);
  // proj: 1536 blocks = 8 XCD x (12 N-panels x 16 M-panels, M inner), 64x64
  gemm_bt<1, 64, 64><<<1536, 256, 0, stream>>>(
      Yb, Wpt, b_proj, nullptr, nullptr, nullptr, out, Ee, Ee);
}